// Round 14
// baseline (1703.668 us; speedup 1.0000x reference)
//
#include <hip/hip_runtime.h>
#include <hip/hip_bf16.h>

// ---------------------------------------------------------------------------
// StreamingQwenMoE round 14: r7 restored (best: 681us) + BARRIER-FREE
// wave-autonomous gate+up GEMM.
//   k_guwf: 4 waves, each owns a private 64-row A slice in per-wave LDS
//   (sAw[4][2][8KB] = 64KB -> 2 blocks/CU) staged by its OWN global_load_lds
//   (vmcnt is wave-local), and loads B fragments DIRECTLY to registers from
//   global f32 (16 rows x 128B coalesced segments; dequant in regs; B panel
//   L2-resident via XCD swizzle; 2x dup across wave-rows affordable at 17%
//   HBM). ZERO s_barrier in the loop; per-wave vmcnt(24) covers loads issued
//   2 tiles back; lgkmcnt(0) guards the 2-buffer WAR before re-staging.
// Mechanism target: the measured plateau is the barrier-coupled per-tile
// drain (r4..r13 all failed to hide it); this removes the coupling.
// Down + shared GEMMs + router/combine: r7 VERBATIM.
// ---------------------------------------------------------------------------

#define TT   2048
#define DD   2048
#define DFF  768
#define DSH  2048
#define EE   32
#define KTOP 8
#define CAP  1024

typedef _Float16 half8  __attribute__((ext_vector_type(8)));
typedef _Float16 half4v __attribute__((ext_vector_type(4)));
typedef float    f32x4  __attribute__((ext_vector_type(4)));

// ---------------- init ------------------------------------------------------
__global__ __launch_bounds__(256) void k_init(int* __restrict__ cnt,
                                              int* __restrict__ slot_tok) {
  int i = blockIdx.x * 256 + threadIdx.x;
  if (i < EE * CAP) slot_tok[i] = 0;
  if (i < EE) cnt[i] = 0;
}

// ---------------- f32 -> f16 cast -------------------------------------------
__global__ __launch_bounds__(256) void k_cast(const float* __restrict__ in,
                                              _Float16* __restrict__ out) {
  int i = blockIdx.x * 256 + threadIdx.x;
  float4 v = ((const float4*)in)[i];
  half4v h = { (_Float16)v.x, (_Float16)v.y, (_Float16)v.z, (_Float16)v.w };
  ((half4v*)out)[i] = h;
}

// ---------------- router: logits, top8, renorm, dispatch --------------------
__global__ __launch_bounds__(64) void k_router(
    const float* __restrict__ x, const float* __restrict__ rw,
    const float* __restrict__ wshg,
    float* __restrict__ shg, int* __restrict__ cnt,
    int* __restrict__ slot_tok, float* __restrict__ slot_w,
    int* __restrict__ slot_pair, int* __restrict__ pair_pos) {
  int t = blockIdx.x;
  int lane = threadIdx.x;
  const float* xr = x + (size_t)t * DD;
  float xv[32];
#pragma unroll
  for (int j = 0; j < 32; ++j) xv[j] = xr[lane + j * 64];

  __shared__ float lg[EE];
  for (int e = 0; e < EE; ++e) {
    const float* we = rw + (size_t)e * DD;
    float s = 0.f;
#pragma unroll
    for (int j = 0; j < 32; ++j) s += xv[j] * we[lane + j * 64];
#pragma unroll
    for (int off = 32; off > 0; off >>= 1) s += __shfl_down(s, off);
    if (lane == 0) lg[e] = s;
  }
  {
    float s = 0.f;
#pragma unroll
    for (int j = 0; j < 32; ++j) s += xv[j] * wshg[lane + j * 64];
#pragma unroll
    for (int off = 32; off > 0; off >>= 1) s += __shfl_down(s, off);
    if (lane == 0) shg[t] = 1.f / (1.f + expf(-s));
  }
  if (lane == 0) {
    unsigned used = 0;
    int sel[KTOP];
    float val[KTOP];
    for (int k = 0; k < KTOP; ++k) {
      float bv = -1e30f; int bi = 0;
      for (int e = 0; e < EE; ++e)
        if (!((used >> e) & 1) && lg[e] > bv) { bv = lg[e]; bi = e; }
      used |= (1u << bi);
      sel[k] = bi; val[k] = bv;
    }
    float mx = val[0], sum = 0.f;
    for (int k = 0; k < KTOP; ++k) { val[k] = expf(val[k] - mx); sum += val[k]; }
    float inv = 1.f / sum;
    for (int k = 0; k < KTOP; ++k) {
      int e = sel[k];
      int pos = atomicAdd(&cnt[e], 1);
      pair_pos[t * KTOP + k] = pos;
      if (pos < CAP) {
        slot_tok[e * CAP + pos] = t;
        slot_w[e * CAP + pos] = val[k] * inv;
        slot_pair[e * CAP + pos] = t * KTOP + k;
      }
    }
  }
}

// ============ gate+up: BARRIER-FREE wave-autonomous (new) ===================
// Each wave: private A slice (64 rows) via its own global_load_lds into
// sAw[wave][2]; B fragments loaded straight to regs from f32 + in-reg dequant.
// No s_barrier in the loop. Per-wave ledger: 8 A-DMA + 16 B-loads per tile,
// issued 2 tiles ahead -> wait vmcnt(24).
template<int NPB, int MBB>
__global__ __launch_bounds__(256, 2) void k_guwf(
    const _Float16* __restrict__ A,
    const float* __restrict__ B0f, const float* __restrict__ B1f,
    const float* __restrict__ S0, const float* __restrict__ S1,
    int sCols, int sStrideE,
    _Float16* __restrict__ OutH,
    int ldA, int ldOut, long long strideBE, long long strideOE,
    const int* __restrict__ cnt, const int* __restrict__ slot_tok) {
  constexpr int KDIM = DD;             // 2048
  constexpr int KT = KDIM / 64;        // 32 (even)

  const int f = blockIdx.x;
  const int xcd = f & 7;
  const int t0 = f >> 3;
  const int mb = t0 % MBB;
  const int pp = t0 / MBB;
  const int p  = pp * 8 + xcd;
  const int nb = p % NPB;
  const int e  = p / NPB;

  const int tid = threadIdx.x;

  int rows = cnt[e] > CAP ? CAP : cnt[e];
  const int rowBase = mb * 128;
  if (rowBase >= rows) return;
  const int nBase = nb * 64;

  const int lane = tid & 63;
  const int wave = tid >> 6;           // 0..3
  const int wr = wave >> 1;            // A rows [wr*64, wr*64+64)
  const int wc = wave & 1;             // B cols [wc*32, wc*32+32) per operand

  __shared__ __align__(16) _Float16 sAw[4][2][4096];   // 64 KB (per-wave A)
  __shared__ float sSc[2][16];

  // scales -> LDS once (single barrier, outside the loop)
  {
    const int sRow = (nBase >> 7) * sCols;
    if (tid < 16)       sSc[0][tid]      = S0[(long long)e * sStrideE + sRow + tid];
    else if (tid < 32)  sSc[1][tid - 16] = S1[(long long)e * sStrideE + sRow + (tid - 16)];
  }
  __syncthreads();

  const float* B0e = B0f + (long long)e * strideBE;
  const float* B1e = B1f + (long long)e * strideBE;

  // per-wave A staging: 8 chunks of 16B (64 rows x 128B), source pre-swizzled
  int aByte[8];
#pragma unroll
  for (int i = 0; i < 8; ++i) {
    int c = lane + i * 64;             // [0,512)
    int lr = c >> 3;                   // local row 0..63
    int colB = ((c & 7) << 4) ^ ((lr & 7) << 4);
    int grow = rowBase + wr * 64 + lr;
    int src = slot_tok[e * CAP + grow];
    aByte[i] = src * (2 * ldA) + colB;
  }
  // B fragment f32 offsets (op-independent): idx = kk*2 + n
  int bOffs[4];
#pragma unroll
  for (int kk = 0; kk < 2; ++kk)
#pragma unroll
    for (int n = 0; n < 2; ++n) {
      int rn = nBase + wc * 32 + n * 16 + (lane & 15);
      bOffs[kk * 2 + n] = rn * KDIM + kk * 32 + (lane >> 4) * 8;
    }

  f32x4 accG[4][2], accU[4][2];
#pragma unroll
  for (int m = 0; m < 4; ++m)
#pragma unroll
    for (int n = 0; n < 2; ++n) {
      accG[m][n] = (f32x4){0.f, 0.f, 0.f, 0.f};
      accU[m][n] = (f32x4){0.f, 0.f, 0.f, 0.f};
    }

  auto stageA = [&](int kt, int buf) {       // 8 DMA (wave-private)
#pragma unroll
    for (int i = 0; i < 8; ++i) {
      __builtin_amdgcn_global_load_lds(
          (const __attribute__((address_space(1))) void*)
              ((const char*)A + aByte[i] + kt * 128),
          (__attribute__((address_space(3))) void*)
              &sAw[wave][buf][(lane + i * 64) * 8],
          16, 0, 0);
    }
  };
  // 16 float4 loads: frag f32 pairs, layout r[((kk*2+o)*2+n)*2 + half]
  auto loadB = [&](int kt, float4 (&r)[16]) {
    const int ko = kt * 64;
#pragma unroll
    for (int kk = 0; kk < 2; ++kk)
#pragma unroll
      for (int o = 0; o < 2; ++o)
#pragma unroll
        for (int n = 0; n < 2; ++n) {
          const float* src = o ? B1e : B0e;
          const float* q = src + bOffs[kk * 2 + n] + ko;
          int idx = ((kk * 2 + o) * 2 + n) * 2;
          r[idx]     = *(const float4*)q;
          r[idx + 1] = *(const float4*)(q + 4);
        }
  };

  // one tile: cvt+MFMA kk0, then cvt kk1 | reissue B | reissue A | MFMA kk1.
  auto tile = [&](int t, float4 (&r)[16]) {
    const char* pA = (const char*)&sAw[wave][t & 1][0];
    float s0 = sSc[0][t >> 1];
    float s1 = sSc[1][t >> 1];
#pragma unroll
    for (int kk = 0; kk < 2; ++kk) {
      // in-register dequant of this kk's 4 fragments
      half8 hg[2], hu[2];
#pragma unroll
      for (int o = 0; o < 2; ++o)
#pragma unroll
        for (int n = 0; n < 2; ++n) {
          int idx = ((kk * 2 + o) * 2 + n) * 2;
          float4 lo = r[idx], hi = r[idx + 1];
          float s = o ? s1 : s0;
          half8 h = { (_Float16)(lo.x * s), (_Float16)(lo.y * s),
                      (_Float16)(lo.z * s), (_Float16)(lo.w * s),
                      (_Float16)(hi.x * s), (_Float16)(hi.y * s),
                      (_Float16)(hi.z * s), (_Float16)(hi.w * s) };
          if (o) hu[n] = h; else hg[n] = h;
        }
      if (kk == 1 && t + 2 < KT) {     // r fully consumed -> reissue (WAR in-order)
        loadB(t + 2, r);
        __builtin_amdgcn_sched_barrier(0);
      }
      // A fragments for this kk (own LDS; compiler inserts lgkm waits)
      const int koffB = kk * 64 + (lane >> 4) * 16;    // bytes
      half8 a[4];
#pragma unroll
      for (int m = 0; m < 4; ++m) {
        int lr = m * 16 + (lane & 15);
        int byt = (lr << 7) + (koffB ^ ((lr & 7) << 4));
        a[m] = *(const half8*)(pA + byt);
      }
      if (kk == 1) {
        asm volatile("s_waitcnt lgkmcnt(0)" ::: "memory");  // reads drained
        __builtin_amdgcn_sched_barrier(0);
        if (t + 2 < KT) stageA(t + 2, t & 1);               // safe WAR re-stage
        __builtin_amdgcn_sched_barrier(0);
      }
#pragma unroll
      for (int m = 0; m < 4; ++m)
#pragma unroll
        for (int n = 0; n < 2; ++n) {
          accG[m][n] = __builtin_amdgcn_mfma_f32_16x16x32_f16(a[m], hg[n], accG[m][n], 0, 0, 0);
          accU[m][n] = __builtin_amdgcn_mfma_f32_16x16x32_f16(a[m], hu[n], accU[m][n], 0, 0, 0);
        }
    }
  };

  float4 rE[16], rO[16];   // named even/odd B sets (rule #20)

  // prologue: tiles 0,1 fully issued (wave-local; 48 VMEM ops)
  loadB(0, rE);  stageA(0, 0);
  loadB(1, rO);  stageA(1, 1);
  __builtin_amdgcn_sched_barrier(0);

  for (int t = 0; t < KT; t += 2) {
    // A(t),B(t) done when only the newest 24 (A(t+1),B(t+1)) may be pending
    if (t + 1 < KT) { asm volatile("s_waitcnt vmcnt(24)" ::: "memory"); }
    else            { asm volatile("s_waitcnt vmcnt(0)"  ::: "memory"); }
    __builtin_amdgcn_sched_barrier(0);
    tile(t, rE);
    if (t + 2 < KT) { asm volatile("s_waitcnt vmcnt(24)" ::: "memory"); }
    else            { asm volatile("s_waitcnt vmcnt(0)"  ::: "memory"); }
    __builtin_amdgcn_sched_barrier(0);
    tile(t + 1, rO);
  }

  // epilogue; C/D layout: col = lane&15, row = (lane>>4)*4 + i (verified)
#pragma unroll
  for (int m = 0; m < 4; ++m) {
#pragma unroll
    for (int i = 0; i < 4; ++i) {
      int row = rowBase + wr * 64 + m * 16 + (lane >> 4) * 4 + i;
      if (row < rows) {
#pragma unroll
        for (int n = 0; n < 2; ++n) {
          int col = nBase + wc * 32 + n * 16 + (lane & 15);
          float gv = accG[m][n][i];
          float uv = accU[m][n][i];
          OutH[(long long)e * strideOE + (long long)row * ldOut + col] =
              (_Float16)((gv / (1.f + __expf(-gv))) * uv);
        }
      }
    }
  }
}

// ============ r7 fused-dequant GEMM (down + shared; verbatim) ===============
template<bool DUAL, bool GATHER, bool DEQ, int EPI, int NPB, int MBB, int KDIM>
__global__ __launch_bounds__(256, 2) void k_gemm(
    const _Float16* __restrict__ A,
    const float* __restrict__ B0f, const float* __restrict__ B1f,
    const float* __restrict__ S0, const float* __restrict__ S1,
    int sCols, int sStrideE,
    _Float16* __restrict__ OutH, float* __restrict__ OutF,
    const float* __restrict__ shg,
    int ldA, int ldOut,
    long long strideAE, long long strideBE, long long strideOE,
    const int* __restrict__ cnt, int rowsConst,
    const int* __restrict__ slot_tok, const float* __restrict__ slot_w) {
  constexpr int BK = 64;
  constexpr int KT = KDIM / BK;
  constexpr int NF = DUAL ? 2 : 4;
  constexpr int BN = DUAL ? 64 : 128;
  constexpr int BCH = DUAL ? 4 : 8;

  const int f = blockIdx.x;
  const int xcd = f & 7;
  const int t0 = f >> 3;
  const int mb = t0 % MBB;
  const int pp = t0 / MBB;
  const int p  = pp * 8 + xcd;
  const int nb = p % NPB;
  const int e  = p / NPB;

  int rows = cnt ? (cnt[e] > CAP ? CAP : cnt[e]) : rowsConst;
  const int rowBase = mb * 128;
  if (rowBase >= rows) return;
  const int nBase = nb * BN;

  const int tid = threadIdx.x;
  const int lane = tid & 63;
  const int wave = tid >> 6;
  const int wr = wave >> 1;
  const int wc = wave & 1;

  __shared__ __align__(16) _Float16 sA[3][8192];
  __shared__ __align__(16) _Float16 sB[2][8192];

  const _Float16* Ae = A + (GATHER ? 0 : (long long)e * strideAE);
  const float* B0e = B0f + (long long)e * strideBE;
  const float* B1e = DUAL ? (B1f + (long long)e * strideBE) : nullptr;
  const float* S0e = DEQ ? (S0 + (long long)e * sStrideE) : nullptr;
  const float* S1e = (DEQ && DUAL) ? (S1 + (long long)e * sStrideE) : nullptr;
  const int sRow = DEQ ? (nBase >> 7) * sCols : 0;

  int aByte[4];
#pragma unroll
  for (int i = 0; i < 4; ++i) {
    int c = tid + i * 256;
    int row = c >> 3;
    int colB = ((c & 7) << 4) ^ ((row & 7) << 4);
    int src = GATHER ? slot_tok[e * CAP + rowBase + row] : (rowBase + row);
    aByte[i] = src * (2 * ldA) + colB;
  }
  int bOff[BCH], wByte[BCH];
#pragma unroll
  for (int i = 0; i < BCH; ++i) {
    int c = tid + i * 256;
    int rn = c >> 4;
    int c4 = (c & 15) << 2;
    bOff[i] = (nBase + rn) * KDIM + c4;
    wByte[i] = ((rn << 7) + (c4 << 1)) ^ ((rn & 7) << 4);
  }

  f32x4 accG[4][NF];
  f32x4 accU[DUAL ? 4 : 1][NF];
#pragma unroll
  for (int m = 0; m < 4; ++m)
#pragma unroll
    for (int n = 0; n < NF; ++n) {
      accG[m][n] = (f32x4){0.f, 0.f, 0.f, 0.f};
      if constexpr (DUAL) accU[m][n] = (f32x4){0.f, 0.f, 0.f, 0.f};
    }

  auto stageA = [&](int kt, int buf) {
#pragma unroll
    for (int i = 0; i < 4; ++i) {
      __builtin_amdgcn_global_load_lds(
          (const __attribute__((address_space(1))) void*)
              ((const char*)Ae + aByte[i] + kt * (BK * 2)),
          (__attribute__((address_space(3))) void*)&sA[buf][(tid + i * 256) * 8],
          16, 0, 0);
    }
  };
  auto loadB = [&](int kt, float4 (&r0)[BCH], float4 (&r1)[BCH]) {
    const int ko = kt * BK;
#pragma unroll
    for (int i = 0; i < BCH; ++i) r0[i] = *(const float4*)(B0e + bOff[i] + ko);
    if constexpr (DUAL) {
#pragma unroll
      for (int i = 0; i < BCH; ++i) r1[i] = *(const float4*)(B1e + bOff[i] + ko);
    }
  };
  auto storeB = [&](int kt, float4 (&r0)[BCH], float4 (&r1)[BCH]) {
    float s0 = 1.f, s1 = 1.f;
    if constexpr (DEQ) {
      s0 = S0e[sRow + (kt >> 1)];
      if constexpr (DUAL) s1 = S1e[sRow + (kt >> 1)];
    }
    char* base = (char*)&sB[kt & 1][0];
#pragma unroll
    for (int i = 0; i < BCH; ++i) {
      half4v h = { (_Float16)(r0[i].x * s0), (_Float16)(r0[i].y * s0),
                   (_Float16)(r0[i].z * s0), (_Float16)(r0[i].w * s0) };
      *(half4v*)(base + wByte[i]) = h;
      if constexpr (DUAL) {
        half4v h1 = { (_Float16)(r1[i].x * s1), (_Float16)(r1[i].y * s1),
                      (_Float16)(r1[i].z * s1), (_Float16)(r1[i].w * s1) };
        *(half4v*)(base + 8192 + wByte[i]) = h1;
      }
    }
  };
  auto computeTile = [&](int ia, int ib) {
    const char* pA = (const char*)&sA[ia][0];
    const char* pB = (const char*)&sB[ib][0];
#pragma unroll
    for (int kk = 0; kk < 2; ++kk) {
      const int koff = kk * 32 + (lane >> 4) * 8;
      half8 a[4];
#pragma unroll
      for (int m = 0; m < 4; ++m) {
        int r = wr * 64 + m * 16 + (lane & 15);
        int byt = ((r << 7) + (koff << 1)) ^ ((r & 7) << 4);
        a[m] = *(const half8*)(pA + byt);
      }
      if constexpr (DUAL) {
        half8 bg[2], bu[2];
#pragma unroll
        for (int n = 0; n < 2; ++n) {
          int rn = wc * 32 + n * 16 + (lane & 15);
          int byt = ((rn << 7) + (koff << 1)) ^ ((rn & 7) << 4);
          bg[n] = *(const half8*)(pB + byt);
          bu[n] = *(const half8*)(pB + 8192 + byt);
        }
#pragma unroll
        for (int m = 0; m < 4; ++m)
#pragma unroll
          for (int n = 0; n < 2; ++n) {
            accG[m][n] = __builtin_amdgcn_mfma_f32_16x16x32_f16(a[m], bg[n], accG[m][n], 0, 0, 0);
            accU[m][n] = __builtin_amdgcn_mfma_f32_16x16x32_f16(a[m], bu[n], accU[m][n], 0, 0, 0);
          }
      } else {
        half8 b[4];
#pragma unroll
        for (int n = 0; n < 4; ++n) {
          int rn = wc * 64 + n * 16 + (lane & 15);
          int byt = ((rn << 7) + (koff << 1)) ^ ((rn & 7) << 4);
          b[n] = *(const half8*)(pB + byt);
        }
#pragma unroll
        for (int m = 0; m < 4; ++m)
#pragma unroll
          for (int n = 0; n < 4; ++n)
            accG[m][n] = __builtin_amdgcn_mfma_f32_16x16x32_f16(a[m], b[n], accG[m][n], 0, 0, 0);
      }
    }
  };

  float4 rbE0[BCH], rbE1[BCH], rbO0[BCH], rbO1[BCH];

  stageA(0, 0); loadB(0, rbE0, rbE1);
  __builtin_amdgcn_sched_barrier(0);
  stageA(1, 1); loadB(1, rbO0, rbO1);
  __builtin_amdgcn_sched_barrier(0);

  int bufC = 0, bufW = 2;

  for (int kt = 0; kt < KT; kt += 2) {
    if (kt + 1 < KT) { asm volatile("s_waitcnt vmcnt(12)" ::: "memory"); }
    else             { asm volatile("s_waitcnt vmcnt(0)"  ::: "memory"); }
    __builtin_amdgcn_sched_barrier(0);
    storeB(kt, rbE0, rbE1);
    asm volatile("s_waitcnt lgkmcnt(0)" ::: "memory");
    __builtin_amdgcn_sched_barrier(0);
    __builtin_amdgcn_s_barrier();
    __builtin_amdgcn_sched_barrier(0);
    if (kt + 2 < KT) { stageA(kt + 2, bufW); loadB(kt + 2, rbE0, rbE1); }
    __builtin_amdgcn_sched_barrier(0);
    computeTile(bufC, 0);
    bufC = (bufC == 2) ? 0 : bufC + 1;
    bufW = (bufW == 2) ? 0 : bufW + 1;

    if (kt + 2 < KT) { asm volatile("s_waitcnt vmcnt(12)" ::: "memory"); }
    else             { asm volatile("s_waitcnt vmcnt(0)"  ::: "memory"); }
    __builtin_amdgcn_sched_barrier(0);
    storeB(kt + 1, rbO0, rbO1);
    asm volatile("s_waitcnt lgkmcnt(0)" ::: "memory");
    __builtin_amdgcn_sched_barrier(0);
    __builtin_amdgcn_s_barrier();
    __builtin_amdgcn_sched_barrier(0);
    if (kt + 3 < KT) { stageA(kt + 3, bufW); loadB(kt + 3, rbO0, rbO1); }
    __builtin_amdgcn_sched_barrier(0);
    computeTile(bufC, 1);
    bufC = (bufC == 2) ? 0 : bufC + 1;
    bufW = (bufW == 2) ? 0 : bufW + 1;
  }

#pragma unroll
  for (int m = 0; m < 4; ++m) {
#pragma unroll
    for (int i = 0; i < 4; ++i) {
      int row = rowBase + wr * 64 + m * 16 + (lane >> 4) * 4 + i;
      if (row < rows) {
        if constexpr (EPI == 1) {
          int pair = slot_tok[e * CAP + row];
          float w = slot_w[e * CAP + row];
#pragma unroll
          for (int n = 0; n < NF; ++n) {
            int col = nBase + wc * 64 + n * 16 + (lane & 15);
            OutH[(long long)pair * DD + col] = (_Float16)(w * accG[m][n][i]);
          }
        } else if constexpr (EPI == 2) {
          float g = shg[row];
#pragma unroll
          for (int n = 0; n < NF; ++n) {
            int col = nBase + wc * 64 + n * 16 + (lane & 15);
            OutF[(long long)row * DD + col] += g * accG[m][n][i];
          }
        } else {
          long long outBase = (long long)e * strideOE;
#pragma unroll
          for (int n = 0; n < NF; ++n) {
            int col = nBase + (DUAL ? wc * 32 : wc * 64) + n * 16 + (lane & 15);
            long long o = outBase + (long long)row * ldOut + col;
            if constexpr (DUAL) {
              float gv = accG[m][n][i];
              float uv = accU[m][n][i];
              OutH[o] = (_Float16)((gv / (1.f + __expf(-gv))) * uv);
            } else {
              OutH[o] = (_Float16)accG[m][n][i];
            }
          }
        }
      }
    }
  }
}

// ---------------- combine: out[t] = sum_k (pos<CAP) Yp[t*8+k] ----------------
__global__ __launch_bounds__(256) void k_combine(
    const _Float16* __restrict__ Yp, const int* __restrict__ pair_pos,
    float* __restrict__ out) {
  int t = blockIdx.x;
  int col = threadIdx.x * 8;
  float acc[8] = {0.f, 0.f, 0.f, 0.f, 0.f, 0.f, 0.f, 0.f};
#pragma unroll
  for (int k = 0; k < KTOP; ++k) {
    if (pair_pos[t * KTOP + k] < CAP) {
      half8 y = *(const half8*)&Yp[((size_t)t * KTOP + k) * DD + col];
#pragma unroll
      for (int j = 0; j < 8; ++j) acc[j] += (float)y[j];
    }
  }
  float4 o0 = {acc[0], acc[1], acc[2], acc[3]};
  float4 o1 = {acc[4], acc[5], acc[6], acc[7]};
  *(float4*)&out[(size_t)t * DD + col] = o0;
  *(float4*)&out[(size_t)t * DD + col + 4] = o1;
}

// ---------------------------------------------------------------------------
extern "C" void kernel_launch(void* const* d_in, const int* in_sizes, int n_in,
                              void* d_out, int out_size, void* d_ws, size_t ws_size,
                              hipStream_t stream) {
  (void)in_sizes; (void)n_in; (void)out_size; (void)ws_size;
  const float* x    = (const float*)d_in[0];
  const float* rw   = (const float*)d_in[1];
  const float* wg   = (const float*)d_in[2];
  const float* sg   = (const float*)d_in[3];
  const float* wu   = (const float*)d_in[4];
  const float* su   = (const float*)d_in[5];
  const float* wd   = (const float*)d_in[6];
  const float* sd   = (const float*)d_in[7];
  const float* wsg  = (const float*)d_in[8];
  const float* wsu  = (const float*)d_in[9];
  const float* wsd  = (const float*)d_in[10];
  const float* wshg = (const float*)d_in[11];
  float* out = (float*)d_out;

  // workspace (~134.5 MB)
  char* p = (char*)d_ws;
  auto alloc = [&](size_t bytes) {
    char* r = p;
    p += (bytes + 255) & ~(size_t)255;
    return r;
  };
  _Float16* x_h   = (_Float16*)alloc((size_t)TT * DD * 2);
  _Float16* H     = (_Float16*)alloc((size_t)EE * CAP * DFF * 2);
  _Float16* Hsh   = (_Float16*)alloc((size_t)TT * DSH * 2);
  _Float16* Yp    = (_Float16*)alloc((size_t)TT * KTOP * DD * 2);
  float* shg      = (float*)alloc((size_t)TT * 4);
  int* cnt        = (int*)alloc((size_t)EE * 4);
  int* slot_tok   = (int*)alloc((size_t)EE * CAP * 4);
  float* slot_w   = (float*)alloc((size_t)EE * CAP * 4);
  int* slot_pair  = (int*)alloc((size_t)EE * CAP * 4);
  int* pair_pos   = (int*)alloc((size_t)TT * KTOP * 4);

  k_init<<<(EE * CAP + 255) / 256, 256, 0, stream>>>(cnt, slot_tok);
  k_cast<<<(TT * DD / 4) / 256, 256, 0, stream>>>(x, x_h);
  k_router<<<TT, 64, 0, stream>>>(x, rw, wshg, shg, cnt, slot_tok, slot_w,
                                  slot_pair, pair_pos);

  // routed gate+up: barrier-free wave-autonomous (NP=12, MB=8 -> 3072 blocks)
  k_guwf<12, 8><<<3072, 256, 0, stream>>>(
      x_h, wg, wu, sg, su, DD / 128, (DFF / 128) * (DD / 128),
      H, DD, DFF, (long long)DFF * DD, (long long)CAP * DFF,
      cnt, slot_tok);

  // routed down -> Yp (r7 fused; pair map via slot_tok arg): 4096 blocks
  k_gemm<false, false, true, 1, 16, 8, DFF><<<4096, 256, 0, stream>>>(
      H, wd, wd, sd, sd, DFF / 128, (DD / 128) * (DFF / 128),
      Yp, nullptr, nullptr,
      DFF, DD,
      (long long)CAP * DFF, (long long)DD * DFF, 0LL,
      cnt, 0, slot_pair, slot_w);

  k_combine<<<TT, 256, 0, stream>>>(Yp, pair_pos, out);

  // shared gate+up (r7): NP=32, MB=16 -> 512 blocks
  k_gemm<true, false, false, 0, 32, 16, DD><<<512, 256, 0, stream>>>(
      x_h, wsg, wsu, nullptr, nullptr, 0, 0,
      Hsh, nullptr, nullptr,
      DD, DSH,
      0LL, 0LL, 0LL,
      nullptr, TT, nullptr, nullptr);

  // shared down (out += shg*val, runs last): NP=16, MB=16 -> 256 blocks
  k_gemm<false, false, false, 2, 16, 16, DSH><<<256, 256, 0, stream>>>(
      Hsh, wsd, wsd, nullptr, nullptr, 0, 0,
      nullptr, out, shg,
      DSH, DD,
      0LL, 0LL, 0LL,
      nullptr, TT, nullptr, nullptr);
}

// Round 15
// 679.660 us; speedup vs baseline: 2.5066x; 2.5066x over previous
//
#include <hip/hip_runtime.h>
#include <hip/hip_bf16.h>

// ---------------------------------------------------------------------------
// StreamingQwenMoE round 15: r7 RESTORED BYTE-IDENTICAL (best measured: 681us).
// Post-r14 map: all nine structural variants regressed or null —
//   r4 fine-phase (-27%), r5/r13 LDS>81920 (1blk/CU, x2 confirmed), r6 depth-3
//   (null), r9 staging-reorder (-12%), r10 co-schedule (null), r11 2x occupancy
//   (null: occupancy doubled, time unchanged), r12 work-pool (-5%), r14
//   barrier-free direct-B (catastrophic: 2.4GB overfetch, uncoalesced frags).
// r7 = hard local optimum of the 2-phase fused-dequant family: per-K-tile
// serial chain (vmcnt + cvt staging + barrier) is structural; waves all wait
// on the same chain regardless of count/placement.
// Components (all verified): f16 MFMA 16x16x32 + C/D layout; router top-8 +
// renorm + atomic slot dispatch; fused block-scale dequant at B staging;
// XOR-swizzled LDS (bank conflicts 4.2e7 -> 0); pre-swizzled global_load_lds
// A staging; bijective XCD block swizzle; counted vmcnt(12) ledger;
// atomic-free pair-buffer combine; LDS = 81920 B exactly (2 blocks/CU).
// ---------------------------------------------------------------------------

#define TT   2048
#define DD   2048
#define DFF  768
#define DSH  2048
#define EE   32
#define KTOP 8
#define CAP  1024

typedef _Float16 half8  __attribute__((ext_vector_type(8)));
typedef _Float16 half4v __attribute__((ext_vector_type(4)));
typedef float    f32x4  __attribute__((ext_vector_type(4)));

// ---------------- init: zero per-expert counters + slot->token map ----------
__global__ __launch_bounds__(256) void k_init(int* __restrict__ cnt,
                                              int* __restrict__ slot_tok) {
  int i = blockIdx.x * 256 + threadIdx.x;
  if (i < EE * CAP) slot_tok[i] = 0;   // unfilled slots -> token 0 (rows masked)
  if (i < EE) cnt[i] = 0;
}

// ---------------- f32 -> f16 cast ---------------------------------------
__global__ __launch_bounds__(256) void k_cast(const float* __restrict__ in,
                                              _Float16* __restrict__ out) {
  int i = blockIdx.x * 256 + threadIdx.x;
  float4 v = ((const float4*)in)[i];
  half4v h = { (_Float16)v.x, (_Float16)v.y, (_Float16)v.z, (_Float16)v.w };
  ((half4v*)out)[i] = h;
}

// ---------------- router: logits, top8, renorm, dispatch --------------------
__global__ __launch_bounds__(64) void k_router(
    const float* __restrict__ x, const float* __restrict__ rw,
    const float* __restrict__ wshg,
    float* __restrict__ shg, int* __restrict__ cnt,
    int* __restrict__ slot_tok, float* __restrict__ slot_w,
    int* __restrict__ slot_pair, int* __restrict__ pair_pos) {
  int t = blockIdx.x;
  int lane = threadIdx.x;
  const float* xr = x + (size_t)t * DD;
  float xv[32];
#pragma unroll
  for (int j = 0; j < 32; ++j) xv[j] = xr[lane + j * 64];

  __shared__ float lg[EE];
  for (int e = 0; e < EE; ++e) {
    const float* we = rw + (size_t)e * DD;
    float s = 0.f;
#pragma unroll
    for (int j = 0; j < 32; ++j) s += xv[j] * we[lane + j * 64];
#pragma unroll
    for (int off = 32; off > 0; off >>= 1) s += __shfl_down(s, off);
    if (lane == 0) lg[e] = s;
  }
  {
    float s = 0.f;
#pragma unroll
    for (int j = 0; j < 32; ++j) s += xv[j] * wshg[lane + j * 64];
#pragma unroll
    for (int off = 32; off > 0; off >>= 1) s += __shfl_down(s, off);
    if (lane == 0) shg[t] = 1.f / (1.f + expf(-s));
  }
  if (lane == 0) {
    unsigned used = 0;
    int sel[KTOP];
    float val[KTOP];
    for (int k = 0; k < KTOP; ++k) {
      float bv = -1e30f; int bi = 0;
      for (int e = 0; e < EE; ++e)
        if (!((used >> e) & 1) && lg[e] > bv) { bv = lg[e]; bi = e; }
      used |= (1u << bi);
      sel[k] = bi; val[k] = bv;
    }
    float mx = val[0], sum = 0.f;
    for (int k = 0; k < KTOP; ++k) { val[k] = expf(val[k] - mx); sum += val[k]; }
    float inv = 1.f / sum;
    for (int k = 0; k < KTOP; ++k) {
      int e = sel[k];
      int pos = atomicAdd(&cnt[e], 1);
      pair_pos[t * KTOP + k] = pos;
      if (pos < CAP) {
        slot_tok[e * CAP + pos] = t;
        slot_w[e * CAP + pos] = val[k] * inv;
        slot_pair[e * CAP + pos] = t * KTOP + k;
      }
    }
  }
}

// ---------------- grouped GEMM: C = A (rows x K, f16) * B (N x K, f32)^T ----
// r3/r7-verified pipeline: sA[3] via global_load_lds (pre-swizzled source),
// sB[2] reg-staged with fused dequant; 1 s_barrier per K-tile; vmcnt(12).
// EPI: 0 = f16 OutH tile; 1 = f16 scatter w*val -> OutH[pair*DD] (pairMap in
// slot_tok arg); 2 = OutF[row] += shg[row]*val.
template<bool DUAL, bool GATHER, bool DEQ, int EPI, int NPB, int MBB, int KDIM>
__global__ __launch_bounds__(256, 2) void k_gemm(
    const _Float16* __restrict__ A,
    const float* __restrict__ B0f, const float* __restrict__ B1f,
    const float* __restrict__ S0, const float* __restrict__ S1,
    int sCols, int sStrideE,
    _Float16* __restrict__ OutH, float* __restrict__ OutF,
    const float* __restrict__ shg,
    int ldA, int ldOut,
    long long strideAE, long long strideBE, long long strideOE,
    const int* __restrict__ cnt, int rowsConst,
    const int* __restrict__ slot_tok, const float* __restrict__ slot_w) {
  constexpr int BK = 64;
  constexpr int KT = KDIM / BK;              // 32 / 12 (all even)
  constexpr int NF = DUAL ? 2 : 4;
  constexpr int BN = DUAL ? 64 : 128;
  constexpr int BCH = DUAL ? 4 : 8;          // float4 staging chunks / thread / op

  // bijective XCD swizzle: all m-blocks of pair (n,e) adjacent on one XCD
  const int f = blockIdx.x;
  const int xcd = f & 7;
  const int t0 = f >> 3;
  const int mb = t0 % MBB;
  const int pp = t0 / MBB;
  const int p  = pp * 8 + xcd;               // (NPB*E) % 8 == 0 for all uses
  const int nb = p % NPB;
  const int e  = p / NPB;

  int rows = cnt ? (cnt[e] > CAP ? CAP : cnt[e]) : rowsConst;
  const int rowBase = mb * 128;
  if (rowBase >= rows) return;
  const int nBase = nb * BN;

  const int tid = threadIdx.x;
  const int lane = tid & 63;
  const int wave = tid >> 6;
  const int wr = wave >> 1;
  const int wc = wave & 1;

  __shared__ __align__(16) _Float16 sA[3][8192];   // 48 KB
  __shared__ __align__(16) _Float16 sB[2][8192];   // 32 KB  (total 81920 B)

  const _Float16* Ae = A + (GATHER ? 0 : (long long)e * strideAE);
  const float* B0e = B0f + (long long)e * strideBE;
  const float* B1e = DUAL ? (B1f + (long long)e * strideBE) : nullptr;
  const float* S0e = DEQ ? (S0 + (long long)e * sStrideE) : nullptr;
  const float* S1e = (DEQ && DUAL) ? (S1 + (long long)e * sStrideE) : nullptr;
  const int sRow = DEQ ? (nBase >> 7) * sCols : 0;

  // A staging (global_load_lds): LDS dest linear, source col pre-swizzled
  int aByte[4];
#pragma unroll
  for (int i = 0; i < 4; ++i) {
    int c = tid + i * 256;                   // 16B chunk id [0,1024)
    int row = c >> 3;                        // tile row 0..127
    int colB = ((c & 7) << 4) ^ ((row & 7) << 4);
    int src = GATHER ? slot_tok[e * CAP + rowBase + row] : (rowBase + row);
    aByte[i] = src * (2 * ldA) + colB;
  }
  // B staging: reg->cvt->swizzled LDS write
  int bOff[BCH], wByte[BCH];
#pragma unroll
  for (int i = 0; i < BCH; ++i) {
    int c = tid + i * 256;
    int rn = c >> 4;                         // [0, BN)
    int c4 = (c & 15) << 2;                  // f32 col 0..60 step 4
    bOff[i] = (nBase + rn) * KDIM + c4;
    wByte[i] = ((rn << 7) + (c4 << 1)) ^ ((rn & 7) << 4);
  }

  f32x4 accG[4][NF];
  f32x4 accU[DUAL ? 4 : 1][NF];
#pragma unroll
  for (int m = 0; m < 4; ++m)
#pragma unroll
    for (int n = 0; n < NF; ++n) {
      accG[m][n] = (f32x4){0.f, 0.f, 0.f, 0.f};
      if constexpr (DUAL) accU[m][n] = (f32x4){0.f, 0.f, 0.f, 0.f};
    }

  auto stageA = [&](int kt, int buf) {       // 4 DMA ops
#pragma unroll
    for (int i = 0; i < 4; ++i) {
      __builtin_amdgcn_global_load_lds(
          (const __attribute__((address_space(1))) void*)
              ((const char*)Ae + aByte[i] + kt * (BK * 2)),
          (__attribute__((address_space(3))) void*)&sA[buf][(tid + i * 256) * 8],
          16, 0, 0);
    }
  };
  auto loadB = [&](int kt, float4 (&r0)[BCH], float4 (&r1)[BCH]) {  // 8 loads
    const int ko = kt * BK;
#pragma unroll
    for (int i = 0; i < BCH; ++i) r0[i] = *(const float4*)(B0e + bOff[i] + ko);
    if constexpr (DUAL) {
#pragma unroll
      for (int i = 0; i < BCH; ++i) r1[i] = *(const float4*)(B1e + bOff[i] + ko);
    }
  };
  auto storeB = [&](int kt, float4 (&r0)[BCH], float4 (&r1)[BCH]) {
    float s0 = 1.f, s1 = 1.f;
    if constexpr (DEQ) {
      s0 = S0e[sRow + (kt >> 1)];
      if constexpr (DUAL) s1 = S1e[sRow + (kt >> 1)];
    }
    char* base = (char*)&sB[kt & 1][0];
#pragma unroll
    for (int i = 0; i < BCH; ++i) {
      half4v h = { (_Float16)(r0[i].x * s0), (_Float16)(r0[i].y * s0),
                   (_Float16)(r0[i].z * s0), (_Float16)(r0[i].w * s0) };
      *(half4v*)(base + wByte[i]) = h;
      if constexpr (DUAL) {
        half4v h1 = { (_Float16)(r1[i].x * s1), (_Float16)(r1[i].y * s1),
                      (_Float16)(r1[i].z * s1), (_Float16)(r1[i].w * s1) };
        *(half4v*)(base + 8192 + wByte[i]) = h1;
      }
    }
  };
  auto computeTile = [&](int ia, int ib) {
    const char* pA = (const char*)&sA[ia][0];
    const char* pB = (const char*)&sB[ib][0];
#pragma unroll
    for (int kk = 0; kk < 2; ++kk) {
      const int koff = kk * 32 + (lane >> 4) * 8;    // f16 elems
      half8 a[4];
#pragma unroll
      for (int m = 0; m < 4; ++m) {
        int r = wr * 64 + m * 16 + (lane & 15);
        int byt = ((r << 7) + (koff << 1)) ^ ((r & 7) << 4);
        a[m] = *(const half8*)(pA + byt);
      }
      if constexpr (DUAL) {
        half8 bg[2], bu[2];
#pragma unroll
        for (int n = 0; n < 2; ++n) {
          int rn = wc * 32 + n * 16 + (lane & 15);
          int byt = ((rn << 7) + (koff << 1)) ^ ((rn & 7) << 4);
          bg[n] = *(const half8*)(pB + byt);
          bu[n] = *(const half8*)(pB + 8192 + byt);
        }
#pragma unroll
        for (int m = 0; m < 4; ++m)
#pragma unroll
          for (int n = 0; n < 2; ++n) {
            accG[m][n] = __builtin_amdgcn_mfma_f32_16x16x32_f16(a[m], bg[n], accG[m][n], 0, 0, 0);
            accU[m][n] = __builtin_amdgcn_mfma_f32_16x16x32_f16(a[m], bu[n], accU[m][n], 0, 0, 0);
          }
      } else {
        half8 b[4];
#pragma unroll
        for (int n = 0; n < 4; ++n) {
          int rn = wc * 64 + n * 16 + (lane & 15);
          int byt = ((rn << 7) + (koff << 1)) ^ ((rn & 7) << 4);
          b[n] = *(const half8*)(pB + byt);
        }
#pragma unroll
        for (int m = 0; m < 4; ++m)
#pragma unroll
          for (int n = 0; n < 4; ++n)
            accG[m][n] = __builtin_amdgcn_mfma_f32_16x16x32_f16(a[m], b[n], accG[m][n], 0, 0, 0);
      }
    }
  };

  // even/odd named register sets (no runtime-indexed reg arrays -> no scratch)
  float4 rbE0[BCH], rbE1[BCH], rbO0[BCH], rbO1[BCH];

  // prologue: tiles 0 and 1 in flight (12 ops each; keep issue groups ordered)
  stageA(0, 0); loadB(0, rbE0, rbE1);
  __builtin_amdgcn_sched_barrier(0);
  stageA(1, 1); loadB(1, rbO0, rbO1);
  __builtin_amdgcn_sched_barrier(0);

  int bufC = 0;   // sA buffer of current tile
  int bufW = 2;   // sA buffer for next issued tile

  for (int kt = 0; kt < KT; kt += 2) {
    // ---------- even tile kt ----------
    if (kt + 1 < KT) { asm volatile("s_waitcnt vmcnt(12)" ::: "memory"); }
    else             { asm volatile("s_waitcnt vmcnt(0)"  ::: "memory"); }
    __builtin_amdgcn_sched_barrier(0);
    storeB(kt, rbE0, rbE1);
    asm volatile("s_waitcnt lgkmcnt(0)" ::: "memory");
    __builtin_amdgcn_sched_barrier(0);
    __builtin_amdgcn_s_barrier();
    __builtin_amdgcn_sched_barrier(0);
    if (kt + 2 < KT) { stageA(kt + 2, bufW); loadB(kt + 2, rbE0, rbE1); }
    __builtin_amdgcn_sched_barrier(0);
    computeTile(bufC, 0);
    bufC = (bufC == 2) ? 0 : bufC + 1;
    bufW = (bufW == 2) ? 0 : bufW + 1;

    // ---------- odd tile kt+1 ----------
    if (kt + 2 < KT) { asm volatile("s_waitcnt vmcnt(12)" ::: "memory"); }
    else             { asm volatile("s_waitcnt vmcnt(0)"  ::: "memory"); }
    __builtin_amdgcn_sched_barrier(0);
    storeB(kt + 1, rbO0, rbO1);
    asm volatile("s_waitcnt lgkmcnt(0)" ::: "memory");
    __builtin_amdgcn_sched_barrier(0);
    __builtin_amdgcn_s_barrier();
    __builtin_amdgcn_sched_barrier(0);
    if (kt + 3 < KT) { stageA(kt + 3, bufW); loadB(kt + 3, rbO0, rbO1); }
    __builtin_amdgcn_sched_barrier(0);
    computeTile(bufC, 1);
    bufC = (bufC == 2) ? 0 : bufC + 1;
    bufW = (bufW == 2) ? 0 : bufW + 1;
  }

  // epilogue; C/D layout: col = lane&15, row = (lane>>4)*4 + i (verified)
#pragma unroll
  for (int m = 0; m < 4; ++m) {
#pragma unroll
    for (int i = 0; i < 4; ++i) {
      int row = rowBase + wr * 64 + m * 16 + (lane >> 4) * 4 + i;
      if (row < rows) {
        if constexpr (EPI == 1) {
          // atomic-free scatter: Yp[pair] = (f16)(w * val); pair map passed
          // via slot_tok arg (slot -> t*8+k). Combine kernel sums per token.
          int pair = slot_tok[e * CAP + row];
          float w = slot_w[e * CAP + row];
#pragma unroll
          for (int n = 0; n < NF; ++n) {
            int col = nBase + wc * 64 + n * 16 + (lane & 15);
            OutH[(long long)pair * DD + col] = (_Float16)(w * accG[m][n][i]);
          }
        } else if constexpr (EPI == 2) {
          float g = shg[row];
#pragma unroll
          for (int n = 0; n < NF; ++n) {
            int col = nBase + wc * 64 + n * 16 + (lane & 15);
            long long o = (long long)row * DD + col;
            OutF[o] += g * accG[m][n][i];
          }
        } else {
          long long outBase = (long long)e * strideOE;
#pragma unroll
          for (int n = 0; n < NF; ++n) {
            int col = nBase + (DUAL ? wc * 32 : wc * 64) + n * 16 + (lane & 15);
            long long o = outBase + (long long)row * ldOut + col;
            if constexpr (DUAL) {
              float gv = accG[m][n][i];
              float uv = accU[m][n][i];
              OutH[o] = (_Float16)((gv / (1.f + __expf(-gv))) * uv);
            } else {
              OutH[o] = (_Float16)accG[m][n][i];
            }
          }
        }
      }
    }
  }
}

// ---------------- combine: out[t] = sum_k (pos<CAP) Yp[t*8+k]  --------------
// (w already folded into Yp by the down-GEMM epilogue; shared-down += after)
__global__ __launch_bounds__(256) void k_combine(
    const _Float16* __restrict__ Yp, const int* __restrict__ pair_pos,
    float* __restrict__ out) {
  int t = blockIdx.x;
  int col = threadIdx.x * 8;
  float acc[8] = {0.f, 0.f, 0.f, 0.f, 0.f, 0.f, 0.f, 0.f};
#pragma unroll
  for (int k = 0; k < KTOP; ++k) {
    if (pair_pos[t * KTOP + k] < CAP) {
      half8 y = *(const half8*)&Yp[((size_t)t * KTOP + k) * DD + col];
#pragma unroll
      for (int j = 0; j < 8; ++j) acc[j] += (float)y[j];
    }
  }
  float4 o0 = {acc[0], acc[1], acc[2], acc[3]};
  float4 o1 = {acc[4], acc[5], acc[6], acc[7]};
  *(float4*)&out[(size_t)t * DD + col] = o0;
  *(float4*)&out[(size_t)t * DD + col + 4] = o1;
}

// ---------------------------------------------------------------------------
extern "C" void kernel_launch(void* const* d_in, const int* in_sizes, int n_in,
                              void* d_out, int out_size, void* d_ws, size_t ws_size,
                              hipStream_t stream) {
  (void)in_sizes; (void)n_in; (void)out_size; (void)ws_size;
  const float* x    = (const float*)d_in[0];
  const float* rw   = (const float*)d_in[1];
  const float* wg   = (const float*)d_in[2];
  const float* sg   = (const float*)d_in[3];
  const float* wu   = (const float*)d_in[4];
  const float* su   = (const float*)d_in[5];
  const float* wd   = (const float*)d_in[6];
  const float* sd   = (const float*)d_in[7];
  const float* wsg  = (const float*)d_in[8];
  const float* wsu  = (const float*)d_in[9];
  const float* wsd  = (const float*)d_in[10];
  const float* wshg = (const float*)d_in[11];
  float* out = (float*)d_out;

  // workspace (~134.5 MB)
  char* p = (char*)d_ws;
  auto alloc = [&](size_t bytes) {
    char* r = p;
    p += (bytes + 255) & ~(size_t)255;
    return r;
  };
  _Float16* x_h   = (_Float16*)alloc((size_t)TT * DD * 2);          //  8.4 MB
  _Float16* H     = (_Float16*)alloc((size_t)EE * CAP * DFF * 2);   // 50.3 MB
  _Float16* Hsh   = (_Float16*)alloc((size_t)TT * DSH * 2);         //  8.4 MB
  _Float16* Yp    = (_Float16*)alloc((size_t)TT * KTOP * DD * 2);   // 67.1 MB
  float* shg      = (float*)alloc((size_t)TT * 4);
  int* cnt        = (int*)alloc((size_t)EE * 4);
  int* slot_tok   = (int*)alloc((size_t)EE * CAP * 4);
  float* slot_w   = (float*)alloc((size_t)EE * CAP * 4);
  int* slot_pair  = (int*)alloc((size_t)EE * CAP * 4);
  int* pair_pos   = (int*)alloc((size_t)TT * KTOP * 4);

  k_init<<<(EE * CAP + 255) / 256, 256, 0, stream>>>(cnt, slot_tok);
  k_cast<<<(TT * DD / 4) / 256, 256, 0, stream>>>(x, x_h);
  k_router<<<TT, 64, 0, stream>>>(x, rw, wshg, shg, cnt, slot_tok, slot_w,
                                  slot_pair, pair_pos);

  // routed gate+up: NP=12, MB=8, E=32 -> 3072 flat blocks
  k_gemm<true, true, true, 0, 12, 8, DD><<<3072, 256, 0, stream>>>(
      x_h, wg, wu, sg, su, DD / 128, (DFF / 128) * (DD / 128),
      H, nullptr, nullptr,
      DD, DFF,
      0LL, (long long)DFF * DD, (long long)CAP * DFF,
      cnt, 0, slot_tok, nullptr);

  // routed down -> Yp (atomic-free; pair map in slot_tok arg): 4096 blocks
  k_gemm<false, false, true, 1, 16, 8, DFF><<<4096, 256, 0, stream>>>(
      H, wd, wd, sd, sd, DFF / 128, (DD / 128) * (DFF / 128),
      Yp, nullptr, nullptr,
      DFF, DD,
      (long long)CAP * DFF, (long long)DD * DFF, 0LL,
      cnt, 0, slot_pair, slot_w);

  // combine: out = sum of each token's 8 weighted pair rows
  k_combine<<<TT, 256, 0, stream>>>(Yp, pair_pos, out);

  // shared gate+up: NP=32, MB=16, E=1 -> 512 blocks
  k_gemm<true, false, false, 0, 32, 16, DD><<<512, 256, 0, stream>>>(
      x_h, wsg, wsu, nullptr, nullptr, 0, 0,
      Hsh, nullptr, nullptr,
      DD, DSH,
      0LL, 0LL, 0LL,
      nullptr, TT, nullptr, nullptr);

  // shared down (out += shg*val, runs last): NP=16, MB=16, E=1 -> 256 blocks
  k_gemm<false, false, false, 2, 16, 16, DSH><<<256, 256, 0, stream>>>(
      Hsh, wsd, wsd, nullptr, nullptr, 0, 0,
      nullptr, out, shg,
      DSH, DD,
      0LL, 0LL, 0LL,
      nullptr, TT, nullptr, nullptr);
}

// Round 16
// 654.543 us; speedup vs baseline: 2.6028x; 1.0384x over previous
//
#include <hip/hip_runtime.h>
#include <hip/hip_bf16.h>

// ---------------------------------------------------------------------------
// StreamingQwenMoE round 16: r7 loop bodies VERBATIM (best: 680us), fused
// dispatch graph to fill ragged-tail idle (Occupancy 16% of 25% ceiling with
// ~45% early-exit blocks):
//   k_gu  = routed gate+up [0,3072) + shared gate+up [3072,3584)
//   k_dn  = routed down [0,4096) + shared down -> Ysh [4096,4352)
//   k_combine2 = out = sum_k keep*Yp + shg*Ysh   (r10-verified)
//   x f32->f16 cast folded into router (row already in registers).
// GEMM inner loop / swizzles / vmcnt ledger / epilogues unchanged from r7;
// bodies moved to a __device__ function (LDS hoisted to wrapper).
// Falsified map: r4 fine-phase, r5/r13 LDS>80K, r6 depth-3, r9 reorder,
// r10 co-regions+deq, r11 2x occupancy, r12 work-pool, r14 barrier-free.
// ---------------------------------------------------------------------------

#define TT   2048
#define DD   2048
#define DFF  768
#define DSH  2048
#define EE   32
#define KTOP 8
#define CAP  1024

typedef _Float16 half8  __attribute__((ext_vector_type(8)));
typedef _Float16 half4v __attribute__((ext_vector_type(4)));
typedef float    f32x4  __attribute__((ext_vector_type(4)));

// ---------------- init: zero per-expert counters + slot->token map ----------
__global__ __launch_bounds__(256) void k_init(int* __restrict__ cnt,
                                              int* __restrict__ slot_tok) {
  int i = blockIdx.x * 256 + threadIdx.x;
  if (i < EE * CAP) slot_tok[i] = 0;   // unfilled slots -> token 0 (rows masked)
  if (i < EE) cnt[i] = 0;
}

// ---------------- router: logits, top8, renorm, dispatch, + x cast ----------
__global__ __launch_bounds__(64) void k_router(
    const float* __restrict__ x, const float* __restrict__ rw,
    const float* __restrict__ wshg,
    _Float16* __restrict__ x_h,
    float* __restrict__ shg, int* __restrict__ cnt,
    int* __restrict__ slot_tok, float* __restrict__ slot_w,
    int* __restrict__ slot_pair, int* __restrict__ pair_pos) {
  int t = blockIdx.x;
  int lane = threadIdx.x;
  const float* xr = x + (size_t)t * DD;
  float xv[32];
#pragma unroll
  for (int j = 0; j < 32; ++j) xv[j] = xr[lane + j * 64];

  // fused f32->f16 cast of this token's row (replaces k_cast dispatch)
#pragma unroll
  for (int j = 0; j < 32; ++j)
    x_h[(size_t)t * DD + lane + j * 64] = (_Float16)xv[j];

  __shared__ float lg[EE];
  for (int e = 0; e < EE; ++e) {
    const float* we = rw + (size_t)e * DD;
    float s = 0.f;
#pragma unroll
    for (int j = 0; j < 32; ++j) s += xv[j] * we[lane + j * 64];
#pragma unroll
    for (int off = 32; off > 0; off >>= 1) s += __shfl_down(s, off);
    if (lane == 0) lg[e] = s;
  }
  {
    float s = 0.f;
#pragma unroll
    for (int j = 0; j < 32; ++j) s += xv[j] * wshg[lane + j * 64];
#pragma unroll
    for (int off = 32; off > 0; off >>= 1) s += __shfl_down(s, off);
    if (lane == 0) shg[t] = 1.f / (1.f + expf(-s));
  }
  if (lane == 0) {
    unsigned used = 0;
    int sel[KTOP];
    float val[KTOP];
    for (int k = 0; k < KTOP; ++k) {
      float bv = -1e30f; int bi = 0;
      for (int e = 0; e < EE; ++e)
        if (!((used >> e) & 1) && lg[e] > bv) { bv = lg[e]; bi = e; }
      used |= (1u << bi);
      sel[k] = bi; val[k] = bv;
    }
    float mx = val[0], sum = 0.f;
    for (int k = 0; k < KTOP; ++k) { val[k] = expf(val[k] - mx); sum += val[k]; }
    float inv = 1.f / sum;
    for (int k = 0; k < KTOP; ++k) {
      int e = sel[k];
      int pos = atomicAdd(&cnt[e], 1);
      pair_pos[t * KTOP + k] = pos;
      if (pos < CAP) {
        slot_tok[e * CAP + pos] = t;
        slot_w[e * CAP + pos] = val[k] * inv;
        slot_pair[e * CAP + pos] = t * KTOP + k;
      }
    }
  }
}

// ---------------- r7 GEMM body (verbatim loop), device function -------------
// C = A (rows x K, f16) * B (N x K, f32)^T. sA[3] via global_load_lds
// (pre-swizzled source), sB[2] reg-staged with fused dequant (s=1 if !DEQ);
// 1 s_barrier per K-tile; counted vmcnt(12).
// EPI: 0 = f16 OutH[outBase + row*ldOut + col] (SwiGLU if DUAL);
//      1 = f16 scatter w*val -> OutH[pair*DD + col] (pair/w via slotBase/W).
template<bool DUAL, bool GATHER, bool DEQ, int EPI, int KDIM>
__device__ __forceinline__ void gemm_body(
    _Float16 (*sA)[8192], _Float16 (*sB)[8192],
    const _Float16* __restrict__ Ae,
    const float* __restrict__ B0e, const float* __restrict__ B1e,
    const float* __restrict__ S0e, const float* __restrict__ S1e, int sRow,
    _Float16* __restrict__ OutH, long long outBase, int ldOut,
    int ldA, int rows, int rowBase, int nBase,
    const int* __restrict__ slotBase, const float* __restrict__ slotW) {
  constexpr int BK = 64;
  constexpr int KT = KDIM / BK;              // 32 / 12 (even)
  constexpr int NF = DUAL ? 2 : 4;
  constexpr int BCH = DUAL ? 4 : 8;          // float4 staging chunks / thread / op

  const int tid = threadIdx.x;
  const int lane = tid & 63;
  const int wave = tid >> 6;
  const int wr = wave >> 1;
  const int wc = wave & 1;

  // A staging (global_load_lds): LDS dest linear, source col pre-swizzled
  int aByte[4];
#pragma unroll
  for (int i = 0; i < 4; ++i) {
    int c = tid + i * 256;                   // 16B chunk id [0,1024)
    int row = c >> 3;                        // tile row 0..127
    int colB = ((c & 7) << 4) ^ ((row & 7) << 4);
    int src = GATHER ? slotBase[rowBase + row] : (rowBase + row);
    aByte[i] = src * (2 * ldA) + colB;
  }
  // B staging: reg->cvt->swizzled LDS write
  int bOff[BCH], wByte[BCH];
#pragma unroll
  for (int i = 0; i < BCH; ++i) {
    int c = tid + i * 256;
    int rn = c >> 4;                         // [0, BN)
    int c4 = (c & 15) << 2;                  // f32 col 0..60 step 4
    bOff[i] = (nBase + rn) * KDIM + c4;
    wByte[i] = ((rn << 7) + (c4 << 1)) ^ ((rn & 7) << 4);
  }

  f32x4 accG[4][NF];
  f32x4 accU[DUAL ? 4 : 1][NF];
#pragma unroll
  for (int m = 0; m < 4; ++m)
#pragma unroll
    for (int n = 0; n < NF; ++n) {
      accG[m][n] = (f32x4){0.f, 0.f, 0.f, 0.f};
      if constexpr (DUAL) accU[m][n] = (f32x4){0.f, 0.f, 0.f, 0.f};
    }

  auto stageA = [&](int kt, int buf) {       // 4 DMA ops
#pragma unroll
    for (int i = 0; i < 4; ++i) {
      __builtin_amdgcn_global_load_lds(
          (const __attribute__((address_space(1))) void*)
              ((const char*)Ae + aByte[i] + kt * (BK * 2)),
          (__attribute__((address_space(3))) void*)&sA[buf][(tid + i * 256) * 8],
          16, 0, 0);
    }
  };
  auto loadB = [&](int kt, float4 (&r0)[BCH], float4 (&r1)[BCH]) {  // 8 loads
    const int ko = kt * BK;
#pragma unroll
    for (int i = 0; i < BCH; ++i) r0[i] = *(const float4*)(B0e + bOff[i] + ko);
    if constexpr (DUAL) {
#pragma unroll
      for (int i = 0; i < BCH; ++i) r1[i] = *(const float4*)(B1e + bOff[i] + ko);
    }
  };
  auto storeB = [&](int kt, float4 (&r0)[BCH], float4 (&r1)[BCH]) {
    float s0 = 1.f, s1 = 1.f;
    if constexpr (DEQ) {
      s0 = S0e[sRow + (kt >> 1)];
      if constexpr (DUAL) s1 = S1e[sRow + (kt >> 1)];
    }
    char* base = (char*)&sB[kt & 1][0];
#pragma unroll
    for (int i = 0; i < BCH; ++i) {
      half4v h = { (_Float16)(r0[i].x * s0), (_Float16)(r0[i].y * s0),
                   (_Float16)(r0[i].z * s0), (_Float16)(r0[i].w * s0) };
      *(half4v*)(base + wByte[i]) = h;
      if constexpr (DUAL) {
        half4v h1 = { (_Float16)(r1[i].x * s1), (_Float16)(r1[i].y * s1),
                      (_Float16)(r1[i].z * s1), (_Float16)(r1[i].w * s1) };
        *(half4v*)(base + 8192 + wByte[i]) = h1;
      }
    }
  };
  auto computeTile = [&](int ia, int ib) {
    const char* pA = (const char*)&sA[ia][0];
    const char* pB = (const char*)&sB[ib][0];
#pragma unroll
    for (int kk = 0; kk < 2; ++kk) {
      const int koff = kk * 32 + (lane >> 4) * 8;    // f16 elems
      half8 a[4];
#pragma unroll
      for (int m = 0; m < 4; ++m) {
        int r = wr * 64 + m * 16 + (lane & 15);
        int byt = ((r << 7) + (koff << 1)) ^ ((r & 7) << 4);
        a[m] = *(const half8*)(pA + byt);
      }
      if constexpr (DUAL) {
        half8 bg[2], bu[2];
#pragma unroll
        for (int n = 0; n < 2; ++n) {
          int rn = wc * 32 + n * 16 + (lane & 15);
          int byt = ((rn << 7) + (koff << 1)) ^ ((rn & 7) << 4);
          bg[n] = *(const half8*)(pB + byt);
          bu[n] = *(const half8*)(pB + 8192 + byt);
        }
#pragma unroll
        for (int m = 0; m < 4; ++m)
#pragma unroll
          for (int n = 0; n < 2; ++n) {
            accG[m][n] = __builtin_amdgcn_mfma_f32_16x16x32_f16(a[m], bg[n], accG[m][n], 0, 0, 0);
            accU[m][n] = __builtin_amdgcn_mfma_f32_16x16x32_f16(a[m], bu[n], accU[m][n], 0, 0, 0);
          }
      } else {
        half8 b[4];
#pragma unroll
        for (int n = 0; n < 4; ++n) {
          int rn = wc * 64 + n * 16 + (lane & 15);
          int byt = ((rn << 7) + (koff << 1)) ^ ((rn & 7) << 4);
          b[n] = *(const half8*)(pB + byt);
        }
#pragma unroll
        for (int m = 0; m < 4; ++m)
#pragma unroll
          for (int n = 0; n < 4; ++n)
            accG[m][n] = __builtin_amdgcn_mfma_f32_16x16x32_f16(a[m], b[n], accG[m][n], 0, 0, 0);
      }
    }
  };

  // even/odd named register sets (rule #20)
  float4 rbE0[BCH], rbE1[BCH], rbO0[BCH], rbO1[BCH];

  // prologue: tiles 0 and 1 in flight (12 ops each; pinned issue groups)
  stageA(0, 0); loadB(0, rbE0, rbE1);
  __builtin_amdgcn_sched_barrier(0);
  stageA(1, 1); loadB(1, rbO0, rbO1);
  __builtin_amdgcn_sched_barrier(0);

  int bufC = 0;   // sA buffer of current tile
  int bufW = 2;   // sA buffer for next issued tile

  for (int kt = 0; kt < KT; kt += 2) {
    // ---------- even tile kt ----------
    if (kt + 1 < KT) { asm volatile("s_waitcnt vmcnt(12)" ::: "memory"); }
    else             { asm volatile("s_waitcnt vmcnt(0)"  ::: "memory"); }
    __builtin_amdgcn_sched_barrier(0);
    storeB(kt, rbE0, rbE1);
    asm volatile("s_waitcnt lgkmcnt(0)" ::: "memory");
    __builtin_amdgcn_sched_barrier(0);
    __builtin_amdgcn_s_barrier();
    __builtin_amdgcn_sched_barrier(0);
    if (kt + 2 < KT) { stageA(kt + 2, bufW); loadB(kt + 2, rbE0, rbE1); }
    __builtin_amdgcn_sched_barrier(0);
    computeTile(bufC, 0);
    bufC = (bufC == 2) ? 0 : bufC + 1;
    bufW = (bufW == 2) ? 0 : bufW + 1;

    // ---------- odd tile kt+1 ----------
    if (kt + 2 < KT) { asm volatile("s_waitcnt vmcnt(12)" ::: "memory"); }
    else             { asm volatile("s_waitcnt vmcnt(0)"  ::: "memory"); }
    __builtin_amdgcn_sched_barrier(0);
    storeB(kt + 1, rbO0, rbO1);
    asm volatile("s_waitcnt lgkmcnt(0)" ::: "memory");
    __builtin_amdgcn_sched_barrier(0);
    __builtin_amdgcn_s_barrier();
    __builtin_amdgcn_sched_barrier(0);
    if (kt + 3 < KT) { stageA(kt + 3, bufW); loadB(kt + 3, rbO0, rbO1); }
    __builtin_amdgcn_sched_barrier(0);
    computeTile(bufC, 1);
    bufC = (bufC == 2) ? 0 : bufC + 1;
    bufW = (bufW == 2) ? 0 : bufW + 1;
  }

  // epilogue; C/D layout: col = lane&15, row = (lane>>4)*4 + i (verified)
#pragma unroll
  for (int m = 0; m < 4; ++m) {
#pragma unroll
    for (int i = 0; i < 4; ++i) {
      int row = rowBase + wr * 64 + m * 16 + (lane >> 4) * 4 + i;
      if (row < rows) {
        if constexpr (EPI == 1) {
          int pair = slotBase[row];
          float w = slotW[row];
#pragma unroll
          for (int n = 0; n < NF; ++n) {
            int col = nBase + wc * 64 + n * 16 + (lane & 15);
            OutH[(long long)pair * DD + col] = (_Float16)(w * accG[m][n][i]);
          }
        } else {
#pragma unroll
          for (int n = 0; n < NF; ++n) {
            int col = nBase + (DUAL ? wc * 32 : wc * 64) + n * 16 + (lane & 15);
            long long o = outBase + (long long)row * ldOut + col;
            if constexpr (DUAL) {
              float gv = accG[m][n][i];
              float uv = accU[m][n][i];
              OutH[o] = (_Float16)((gv / (1.f + __expf(-gv))) * uv);
            } else {
              OutH[o] = (_Float16)accG[m][n][i];
            }
          }
        }
      }
    }
  }
}

// ---------------- fused gate+up: routed [0,3072) | shared [3072,3584) -------
__global__ __launch_bounds__(256, 2) void k_gu(
    const _Float16* __restrict__ x_h,
    const float* __restrict__ wg, const float* __restrict__ wu,
    const float* __restrict__ sg, const float* __restrict__ su,
    _Float16* __restrict__ H,
    const float* __restrict__ wsg, const float* __restrict__ wsu,
    _Float16* __restrict__ Hsh,
    const int* __restrict__ cnt, const int* __restrict__ slot_tok) {
  __shared__ __align__(16) _Float16 sA[3][8192];   // 48 KB
  __shared__ __align__(16) _Float16 sB[2][8192];   // 32 KB (total 81920 B)
  const int bid = blockIdx.x;
  if (bid < 3072) {
    // routed: bijective XCD swizzle, NPB=12, MBB=8
    const int xcd = bid & 7, t0 = bid >> 3;
    const int mb = t0 % 8, pp = t0 / 8;
    const int p = pp * 8 + xcd;              // [0,384)
    const int nb = p % 12, e = p / 12;
    int rows = cnt[e] > CAP ? CAP : cnt[e];
    const int rowBase = mb * 128;
    if (rowBase >= rows) return;
    gemm_body<true, true, true, 0, DD>(
        sA, sB, x_h,
        wg + (long long)e * DFF * DD, wu + (long long)e * DFF * DD,
        sg + (long long)e * ((DFF / 128) * (DD / 128)),
        su + (long long)e * ((DFF / 128) * (DD / 128)),
        ((nb * 64) >> 7) * (DD / 128),
        H, (long long)e * CAP * DFF, DFF,
        DD, rows, rowBase, nb * 64,
        slot_tok + e * CAP, nullptr);
  } else {
    // shared: NPB=32, MBB=16 (512 blocks)
    const int f = bid - 3072;
    const int xcd = f & 7, t0 = f >> 3;
    const int mb = t0 % 16, pp = t0 / 16;
    const int nb = pp * 8 + xcd;             // [0,32)
    gemm_body<true, false, false, 0, DD>(
        sA, sB, x_h,
        wsg, wsu, nullptr, nullptr, 0,
        Hsh, 0LL, DSH,
        DD, TT, mb * 128, nb * 64,
        nullptr, nullptr);
  }
}

// ---------------- fused down: routed [0,4096) | shared -> Ysh [4096,4352) ---
__global__ __launch_bounds__(256, 2) void k_dn(
    const _Float16* __restrict__ H,
    const float* __restrict__ wd, const float* __restrict__ sd,
    _Float16* __restrict__ Yp,
    const _Float16* __restrict__ Hsh, const float* __restrict__ wsd,
    _Float16* __restrict__ Ysh,
    const int* __restrict__ cnt,
    const int* __restrict__ slot_pair, const float* __restrict__ slot_w) {
  __shared__ __align__(16) _Float16 sA[3][8192];
  __shared__ __align__(16) _Float16 sB[2][8192];
  const int bid = blockIdx.x;
  if (bid < 4096) {
    // routed down: NPB=16, MBB=8
    const int xcd = bid & 7, t0 = bid >> 3;
    const int mb = t0 % 8, pp = t0 / 8;
    const int p = pp * 8 + xcd;              // [0,512)
    const int nb = p % 16, e = p / 16;
    int rows = cnt[e] > CAP ? CAP : cnt[e];
    const int rowBase = mb * 128;
    if (rowBase >= rows) return;
    gemm_body<false, false, true, 1, DFF>(
        sA, sB, H + (long long)e * CAP * DFF,
        wd + (long long)e * DD * DFF, wd + (long long)e * DD * DFF,
        sd + (long long)e * ((DD / 128) * (DFF / 128)), nullptr,
        ((nb * 128) >> 7) * (DFF / 128),
        Yp, 0LL, DD,
        DFF, rows, rowBase, nb * 128,
        slot_pair + e * CAP, slot_w + e * CAP);
  } else {
    // shared down: NPB=16, MBB=16 (256 blocks) -> Ysh (plain f16 tile)
    const int f = bid - 4096;
    const int xcd = f & 7, t0 = f >> 3;      // t0 in [0,32)
    const int mb = t0 % 16, pp = t0 / 16;
    const int nb = pp * 8 + xcd;             // [0,16)
    gemm_body<false, false, false, 0, DSH>(
        sA, sB, Hsh,
        wsd, wsd, nullptr, nullptr, 0,
        Ysh, 0LL, DD,
        DSH, TT, mb * 128, nb * 128,
        nullptr, nullptr);
  }
}

// ---------------- combine2: out = sum_k keep*Yp + shg*Ysh (r10-verified) ----
__global__ __launch_bounds__(256) void k_combine2(
    const _Float16* __restrict__ Yp, const _Float16* __restrict__ Ysh,
    const float* __restrict__ shg, const int* __restrict__ pair_pos,
    float* __restrict__ out) {
  int t = blockIdx.x;
  int col = threadIdx.x * 8;
  float acc[8];
  half8 ys = *(const half8*)&Ysh[(size_t)t * DD + col];
  float g = shg[t];
#pragma unroll
  for (int j = 0; j < 8; ++j) acc[j] = g * (float)ys[j];
#pragma unroll
  for (int k = 0; k < KTOP; ++k) {
    if (pair_pos[t * KTOP + k] < CAP) {
      half8 y = *(const half8*)&Yp[((size_t)t * KTOP + k) * DD + col];
#pragma unroll
      for (int j = 0; j < 8; ++j) acc[j] += (float)y[j];
    }
  }
  float4 o0 = {acc[0], acc[1], acc[2], acc[3]};
  float4 o1 = {acc[4], acc[5], acc[6], acc[7]};
  *(float4*)&out[(size_t)t * DD + col] = o0;
  *(float4*)&out[(size_t)t * DD + col + 4] = o1;
}

// ---------------------------------------------------------------------------
extern "C" void kernel_launch(void* const* d_in, const int* in_sizes, int n_in,
                              void* d_out, int out_size, void* d_ws, size_t ws_size,
                              hipStream_t stream) {
  (void)in_sizes; (void)n_in; (void)out_size; (void)ws_size;
  const float* x    = (const float*)d_in[0];
  const float* rw   = (const float*)d_in[1];
  const float* wg   = (const float*)d_in[2];
  const float* sg   = (const float*)d_in[3];
  const float* wu   = (const float*)d_in[4];
  const float* su   = (const float*)d_in[5];
  const float* wd   = (const float*)d_in[6];
  const float* sd   = (const float*)d_in[7];
  const float* wsg  = (const float*)d_in[8];
  const float* wsu  = (const float*)d_in[9];
  const float* wsd  = (const float*)d_in[10];
  const float* wshg = (const float*)d_in[11];
  float* out = (float*)d_out;

  // workspace (~143 MB)
  char* p = (char*)d_ws;
  auto alloc = [&](size_t bytes) {
    char* r = p;
    p += (bytes + 255) & ~(size_t)255;
    return r;
  };
  _Float16* x_h   = (_Float16*)alloc((size_t)TT * DD * 2);          //  8.4 MB
  _Float16* H     = (_Float16*)alloc((size_t)EE * CAP * DFF * 2);   // 50.3 MB
  _Float16* Hsh   = (_Float16*)alloc((size_t)TT * DSH * 2);         //  8.4 MB
  _Float16* Yp    = (_Float16*)alloc((size_t)TT * KTOP * DD * 2);   // 67.1 MB
  _Float16* Ysh   = (_Float16*)alloc((size_t)TT * DD * 2);          //  8.4 MB
  float* shg      = (float*)alloc((size_t)TT * 4);
  int* cnt        = (int*)alloc((size_t)EE * 4);
  int* slot_tok   = (int*)alloc((size_t)EE * CAP * 4);
  float* slot_w   = (float*)alloc((size_t)EE * CAP * 4);
  int* slot_pair  = (int*)alloc((size_t)EE * CAP * 4);
  int* pair_pos   = (int*)alloc((size_t)TT * KTOP * 4);

  k_init<<<(EE * CAP + 255) / 256, 256, 0, stream>>>(cnt, slot_tok);
  k_router<<<TT, 64, 0, stream>>>(x, rw, wshg, x_h, shg, cnt, slot_tok,
                                  slot_w, slot_pair, pair_pos);

  // fused gate+up: routed (3072) + shared (512)
  k_gu<<<3584, 256, 0, stream>>>(x_h, wg, wu, sg, su, H, wsg, wsu, Hsh,
                                 cnt, slot_tok);

  // fused down: routed (4096) + shared->Ysh (256)
  k_dn<<<4352, 256, 0, stream>>>(H, wd, sd, Yp, Hsh, wsd, Ysh,
                                 cnt, slot_pair, slot_w);

  // combine: out = sum_k keep*Yp + shg*Ysh
  k_combine2<<<TT, 256, 0, stream>>>(Yp, Ysh, shg, pair_pos, out);
}